// Round 11
// baseline (110.235 us; speedup 1.0000x reference)
//
#include <hip/hip_runtime.h>
#include <hip/hip_bf16.h>
#include <math.h>

// OLCNN: x(B,1,9,9) -> conv3x3(16ch) -> sigmoid -> maxpool2x2 floor (7x7->3x3)
//        -> conv2 (144->32) via MFMA -> sigmoid -> fc 32->4.  B = 131072 fp32.
//
// Round 11 — 2 lanes per sample => 4 waves/SIMD:
//  * R10 landed ~40us main vs ~12us issue floor: pure latency exposure at
//    2 waves/SIMD, and wave count is pinned by samples/wave. Halve it:
//    wave = 32 samples, lane half h computes conv1 channels 8h..8h+7
//    (band features k = 24h..24h+23, 12 pk dwords/lane).
//  * MFMA: one 32x32 M-tile (acc 16), 3 MFMA/band. A-frags need only 4
//    shuffles/band: each lane exports pk[4..7] via shfl_xor(32);
//    kb0 = h0?pk[0..3]:recv, kb1 = h0?pk[8..11]:pk[0..3],
//    kb2 = h0?recv:pk[8..11].  Same k-order as prep B layout => R8's
//    verified A/B-map cancellation still holds.
//  * amdgpu_waves_per_eu(4,4): VGPR budget 128. Dropped the xbn double
//    buffer (TLP hides x latency now); live set ~115 regs.
//  * epilogue: 32-row LDS transpose (2-way = free), each lane computes 2 of
//    4 fc outputs, float2 store (wave writes 32 x 16B contiguous).

typedef float v2f __attribute__((ext_vector_type(2)));
typedef float f4  __attribute__((ext_vector_type(4)));
typedef f4 uf4 __attribute__((aligned(4)));   // align-4 dwordx4 (x rows 4B-aligned)
typedef __bf16 bf16x2 __attribute__((ext_vector_type(2)));
typedef __bf16 bf16x8 __attribute__((ext_vector_type(8)));
typedef float f32x16 __attribute__((ext_vector_type(16)));
typedef unsigned int u32;
typedef u32 u32x4 __attribute__((ext_vector_type(4)));

#define BLOCK 256                 // 4 waves, 128 samples per block
#define LOG2E 1.4426950408889634f

// ws layout:
//   bytes  [0 .. 9216): w2 B-frags bf16 [pi][kb][lane][j]  (3*3*64*8 u16)
//   floats [2304 .. 2624): small block staged to LDS:
#define OFF_SMALL 2304
#define S_W1P  0      // [8][9][2]  w1 * log2e, ch-paired
#define S_B1P  144    // [8][2]     b1 * log2e, ch-paired
#define S_FCWP 160    // [4][16][2] fc_w ch-paired
#define S_B2S  288    // [32]       b2 * log2e
#define SMALL_FLOATS 320
#define PREP_ITEMS (4608 + SMALL_FLOATS)

__device__ __forceinline__ float sig2(float s) {
    // arg pre-scaled by log2e: sigmoid = 1/(1+2^-s)
    return __builtin_amdgcn_rcpf(1.0f + __builtin_amdgcn_exp2f(-s));
}

__device__ __forceinline__ u32 pack_bf(float a, float b) {
    bf16x2 p; p.x = (__bf16)a; p.y = (__bf16)b;
    return __builtin_bit_cast(u32, p);
}

__global__ void prep_kernel(const float* __restrict__ w1,
                            const float* __restrict__ b1,
                            const float* __restrict__ w2,
                            const float* __restrict__ b2,
                            const float* __restrict__ fcw,
                            float* __restrict__ ws) {
    int i = blockIdx.x * blockDim.x + threadIdx.x;
    if (i < 4608) {
        // B-frag: value at (pi, kb, lane, j) = w2[oc = lane&31][d] * log2e,
        // band-feature k = kb*16 + (lane>>5)*8 + j, d = (k/3)*9 + pi*3 + k%3
        int j = i & 7, lane = (i >> 3) & 63, kb = (i >> 9) % 3, pi = i / 1536;
        int k = kb * 16 + (lane >> 5) * 8 + j;
        int o = k / 3, pj = k - 3 * o;
        float v = w2[(lane & 31) * 144 + o * 9 + pi * 3 + pj] * LOG2E;
        ((__bf16*)ws)[i] = (__bf16)v;            // RNE convert
    } else if (i < PREP_ITEMS) {
        int r = i - 4608;
        float v;
        if (r < S_B1P) {                         // w1 ch-paired: [op][k][h]
            int h = r & 1, k = (r >> 1) % 9, op = (r >> 1) / 9;
            v = w1[(2 * op + h) * 9 + k] * LOG2E;
        } else if (r < S_FCWP) {                 // b1 ch-paired: [op][h]
            int q = r - S_B1P;
            v = b1[2 * (q >> 1) + (q & 1)] * LOG2E;
        } else if (r < S_B2S) {                  // fcw ch-paired: [row][j][h]
            int q = r - S_FCWP;
            int h = q & 1, j = (q >> 1) % 16, rr = (q >> 1) / 16;
            v = fcw[rr * 32 + 2 * j + h];
        } else {                                 // b2 * log2e
            v = b2[r - S_B2S] * LOG2E;
        }
        ws[OFF_SMALL + r] = v;
    }
}

__global__ __launch_bounds__(BLOCK)
__attribute__((amdgpu_waves_per_eu(4, 4)))
void olcnn_kernel(
    const float* __restrict__ xg,   // (B,81)
    const float* __restrict__ wsf,  // prep output
    const float* __restrict__ fcb,  // (4,)
    float* __restrict__ out)        // (B,4)
{
    // epilogue-only scratch: 32 rows x 34 dw per wave
    __shared__ u32 lds_scr[4 * 1088];
    __shared__ __align__(16) float lws[SMALL_FLOATS];

    const int tid  = threadIdx.x;
    const int lane = tid & 63;
    const int wid  = tid >> 6;
    const int h    = lane >> 5;          // half: conv1 channels 8h..8h+7
    const bool h0  = (h == 0);
    const int s    = lane & 31;          // sample-in-wave
    u32* scr = lds_scr + wid * 1088;

    if (tid < SMALL_FLOATS / 4)
        ((f4*)lws)[tid] = ((const f4*)(wsf + OFF_SMALL))[tid];
    __syncthreads();

    const v2f* w1p  = (const v2f*)(lws + S_W1P);
    const v2f* b1p  = (const v2f*)(lws + S_B1P);
    const v2f* fcwp = (const v2f*)(lws + S_FCWP);

    const int samp = blockIdx.x * 128 + wid * 32 + s;   // this lane's sample
    const float* xs = xg + (long long)samp * 81;

    const u32x4* bfrag_g = (const u32x4*)wsf;   // [pi*3+kb][lane] x 16B

    f32x16 acc{};                        // rows = samples 0..31 of this wave

    #pragma unroll 1                     // rolled: body fits I$
    for (int pi = 0; pi < 3; ++pi) {
        // ---- x band rows 2pi..2pi+3, cols 0..7 (both halves load the same
        //      sample; 2nd half hits L1). Pinned vs remat. ----
        float xb[4][8];
        #pragma unroll
        for (int r = 0; r < 4; ++r) {
            const float* rp = xs + (2 * pi + r) * 9;
            f4 a = *(const uf4*)rp;
            f4 b = *(const uf4*)(rp + 4);
            xb[r][0] = a.x; xb[r][1] = a.y; xb[r][2] = a.z; xb[r][3] = a.w;
            xb[r][4] = b.x; xb[r][5] = b.y; xb[r][6] = b.z; xb[r][7] = b.w;
        }
        #pragma unroll
        for (int r = 0; r < 4; ++r)
            #pragma unroll
            for (int c = 0; c < 8; ++c)
                asm volatile("" : "+v"(xb[r][c]));

        // this band's B-fragments (12 VGPRs), issued early
        u32x4 bfr[3];
        #pragma unroll
        for (int kb = 0; kb < 3; ++kb)
            bfr[kb] = bfrag_g[(pi * 3 + kb) * 64 + lane];

        // ---- conv1 (channels 8h..8h+7) + pool + sigmoid -> pk[12] ----
        // local feature ff = c*3+pj (c = local channel 0..7), global
        // k = 24h + ff; pk dword d covers ff = 2d, 2d+1.
        u32 pk[12];
        #pragma unroll
        for (int opl = 0; opl < 4; ++opl) {      // local channel pair
            const int gop = 4 * h + opl;         // global pair index
            v2f wv[9];
            #pragma unroll
            for (int k = 0; k < 9; ++k) wv[k] = w1p[gop * 9 + k];
            const v2f bb = b1p[gop];
            v2f vm[3];
            #pragma unroll
            for (int pj = 0; pj < 3; ++pj) {
                v2f vmax;
                #pragma unroll
                for (int dh = 0; dh < 2; ++dh)
                    #pragma unroll
                    for (int dw = 0; dw < 2; ++dw) {
                        v2f sacc = bb;
                        #pragma unroll
                        for (int i = 0; i < 3; ++i)
                            #pragma unroll
                            for (int jj = 0; jj < 3; ++jj) {
                                float xv = xb[dh + i][2 * pj + dw + jj];
                                sacc = __builtin_elementwise_fma(
                                           (v2f){xv, xv}, wv[i * 3 + jj], sacc);
                            }
                        if (dh == 0 && dw == 0) vmax = sacc;
                        else vmax = __builtin_elementwise_max(vmax, sacc);
                    }
                vm[pj] = vmax;
            }
            float s00 = sig2(vm[0].x), s01 = sig2(vm[1].x), s02 = sig2(vm[2].x);
            float s10 = sig2(vm[0].y), s11 = sig2(vm[1].y), s12 = sig2(vm[2].y);
            pk[3 * opl + 0] = pack_bf(s00, s01);
            pk[3 * opl + 1] = pack_bf(s02, s10);
            pk[3 * opl + 2] = pack_bf(s11, s12);
        }

        // ---- half-swap of pk[4..7]; A-frags; 3 MFMA ----
        u32 recv[4];
        #pragma unroll
        for (int i = 0; i < 4; ++i)
            recv[i] = (u32)__shfl_xor((int)pk[4 + i], 32);

        #pragma unroll
        for (int kb = 0; kb < 3; ++kb) {
            u32 ad[4];
            #pragma unroll
            for (int i = 0; i < 4; ++i) {
                ad[i] = (kb == 0) ? (h0 ? pk[i]     : recv[i])
                      : (kb == 1) ? (h0 ? pk[8 + i] : pk[i])
                                  : (h0 ? recv[i]   : pk[8 + i]);
            }
            u32x4 aw; aw.x = ad[0]; aw.y = ad[1]; aw.z = ad[2]; aw.w = ad[3];
            acc = __builtin_amdgcn_mfma_f32_32x32x16_bf16(
                      __builtin_bit_cast(bf16x8, aw),
                      __builtin_bit_cast(bf16x8, bfr[kb]), acc, 0, 0, 0);
        }
    }

    // ---- bias + sigmoid on C-layout regs, transpose via LDS ----
    // C/D: col(oc) = lane&31, row(sample) = (reg&3)+8*(reg>>2)+4*(lane>>5)
    const float b2v = lws[S_B2S + s];
    #pragma unroll
    for (int r = 0; r < 16; ++r) {
        const int srow = (r & 3) + 8 * (r >> 2) + 4 * h;
        scr[srow * 34 + s] = __builtin_bit_cast(u32, sig2(acc[r] + b2v));
    }

    // ---- fc: lane handles sample s, outputs 2h and 2h+1 ----
    v2f h2[16];
    #pragma unroll
    for (int j = 0; j < 16; ++j)
        h2[j] = *(const v2f*)((const float*)scr + s * 34 + 2 * j);

    const v2f* fA = fcwp + (2 * h) * 16;
    const v2f* fB = fcwp + (2 * h + 1) * 16;
    v2f aA = h2[0] * fA[0], aB = h2[0] * fB[0];
    #pragma unroll
    for (int j = 1; j < 16; ++j) {
        aA = __builtin_elementwise_fma(h2[j], fA[j], aA);
        aB = __builtin_elementwise_fma(h2[j], fB[j], aB);
    }
    float2 res = make_float2(fcb[2 * h] + aA.x + aA.y,
                             fcb[2 * h + 1] + aB.x + aB.y);
    ((float2*)out)[samp * 2 + h] = res;
}

extern "C" void kernel_launch(void* const* d_in, const int* in_sizes, int n_in,
                              void* d_out, int out_size, void* d_ws, size_t ws_size,
                              hipStream_t stream) {
    const float* x   = (const float*)d_in[0];
    const float* w1  = (const float*)d_in[1];
    const float* b1  = (const float*)d_in[2];
    const float* w2  = (const float*)d_in[3];
    const float* b2  = (const float*)d_in[4];
    const float* fcw = (const float*)d_in[5];
    const float* fcb = (const float*)d_in[6];
    float* out = (float*)d_out;
    float* ws  = (float*)d_ws;        // ~10.5 KB used

    prep_kernel<<<dim3((PREP_ITEMS + 255) / 256), dim3(256), 0, stream>>>(
        w1, b1, w2, b2, fcw, ws);

    const int nB = in_sizes[0] / 81;  // 131072; 128 samples per block
    olcnn_kernel<<<dim3(nB / 128), dim3(BLOCK), 0, stream>>>(x, ws, fcb, out);
}

// Round 12
// 106.875 us; speedup vs baseline: 1.0314x; 1.0314x over previous
//
#include <hip/hip_runtime.h>
#include <hip/hip_bf16.h>
#include <math.h>

// OLCNN: x(B,1,9,9) -> conv3x3(16ch) -> sigmoid -> maxpool2x2 floor (7x7->3x3)
//        -> conv2 (144->32) via MFMA -> sigmoid -> fc 32->4.  B = 131072 fp32.
//
// Round 12 — R11 split, spill-proofed + latency-covered:
//  * 2 lanes/sample (32 samples/wave, 4096 waves): lane half h computes conv1
//    channels 8h..8h+7 (pk[12]); one 32x32 MFMA M-tile, 3 MFMA/band; 4
//    shuffles/band for the A-frag half-swap (R8-verified A/B k-map
//    cancellation untouched).
//  * amdgpu_waves_per_eu(3,3): ~170 VGPR budget — R11's (4,4) forced 128 and
//    likely spilled (R9 disease, invisible under the fills). 3 waves/SIMD is
//    still 1.5x R10's occupancy, guaranteed spill-free.
//  * x prefetch restored (R10-proven): band pi+1's 8 dwordx4 loads issue at
//    the top of band pi + sched_barrier(0); R11 dropped this and exposed
//    ~900cyc HBM latency per band (3x/wave) — enough to cancel its
//    occupancy gain.
//  * epilogue: 32-row LDS transpose, lane computes 2 of 4 fc outputs,
//    float2 store.

typedef float v2f __attribute__((ext_vector_type(2)));
typedef float f4  __attribute__((ext_vector_type(4)));
typedef f4 uf4 __attribute__((aligned(4)));   // align-4 dwordx4 (x rows 4B-aligned)
typedef __bf16 bf16x2 __attribute__((ext_vector_type(2)));
typedef __bf16 bf16x8 __attribute__((ext_vector_type(8)));
typedef float f32x16 __attribute__((ext_vector_type(16)));
typedef unsigned int u32;
typedef u32 u32x4 __attribute__((ext_vector_type(4)));

#define BLOCK 256                 // 4 waves, 128 samples per block
#define LOG2E 1.4426950408889634f

// ws layout:
//   bytes  [0 .. 9216): w2 B-frags bf16 [pi][kb][lane][j]  (3*3*64*8 u16)
//   floats [2304 .. 2624): small block staged to LDS:
#define OFF_SMALL 2304
#define S_W1P  0      // [8][9][2]  w1 * log2e, ch-paired
#define S_B1P  144    // [8][2]     b1 * log2e, ch-paired
#define S_FCWP 160    // [4][16][2] fc_w ch-paired
#define S_B2S  288    // [32]       b2 * log2e
#define SMALL_FLOATS 320
#define PREP_ITEMS (4608 + SMALL_FLOATS)

__device__ __forceinline__ float sig2(float s) {
    // arg pre-scaled by log2e: sigmoid = 1/(1+2^-s)
    return __builtin_amdgcn_rcpf(1.0f + __builtin_amdgcn_exp2f(-s));
}

__device__ __forceinline__ u32 pack_bf(float a, float b) {
    bf16x2 p; p.x = (__bf16)a; p.y = (__bf16)b;
    return __builtin_bit_cast(u32, p);
}

__global__ void prep_kernel(const float* __restrict__ w1,
                            const float* __restrict__ b1,
                            const float* __restrict__ w2,
                            const float* __restrict__ b2,
                            const float* __restrict__ fcw,
                            float* __restrict__ ws) {
    int i = blockIdx.x * blockDim.x + threadIdx.x;
    if (i < 4608) {
        // B-frag: value at (pi, kb, lane, j) = w2[oc = lane&31][d] * log2e,
        // band-feature k = kb*16 + (lane>>5)*8 + j, d = (k/3)*9 + pi*3 + k%3
        int j = i & 7, lane = (i >> 3) & 63, kb = (i >> 9) % 3, pi = i / 1536;
        int k = kb * 16 + (lane >> 5) * 8 + j;
        int o = k / 3, pj = k - 3 * o;
        float v = w2[(lane & 31) * 144 + o * 9 + pi * 3 + pj] * LOG2E;
        ((__bf16*)ws)[i] = (__bf16)v;            // RNE convert
    } else if (i < PREP_ITEMS) {
        int r = i - 4608;
        float v;
        if (r < S_B1P) {                         // w1 ch-paired: [op][k][h]
            int h = r & 1, k = (r >> 1) % 9, op = (r >> 1) / 9;
            v = w1[(2 * op + h) * 9 + k] * LOG2E;
        } else if (r < S_FCWP) {                 // b1 ch-paired: [op][h]
            int q = r - S_B1P;
            v = b1[2 * (q >> 1) + (q & 1)] * LOG2E;
        } else if (r < S_B2S) {                  // fcw ch-paired: [row][j][h]
            int q = r - S_FCWP;
            int h = q & 1, j = (q >> 1) % 16, rr = (q >> 1) / 16;
            v = fcw[rr * 32 + 2 * j + h];
        } else {                                 // b2 * log2e
            v = b2[r - S_B2S] * LOG2E;
        }
        ws[OFF_SMALL + r] = v;
    }
}

#define LOADB(dst, pi_)                                              \
    do {                                                             \
        _Pragma("unroll")                                            \
        for (int r_ = 0; r_ < 4; ++r_) {                             \
            const float* rp_ = xs + (2 * (pi_) + r_) * 9;            \
            f4 a_ = *(const uf4*)rp_;                                \
            f4 b_ = *(const uf4*)(rp_ + 4);                          \
            dst[r_][0] = a_.x; dst[r_][1] = a_.y;                    \
            dst[r_][2] = a_.z; dst[r_][3] = a_.w;                    \
            dst[r_][4] = b_.x; dst[r_][5] = b_.y;                    \
            dst[r_][6] = b_.z; dst[r_][7] = b_.w;                    \
        }                                                            \
    } while (0)

__global__ __launch_bounds__(BLOCK)
__attribute__((amdgpu_waves_per_eu(3, 3)))
void olcnn_kernel(
    const float* __restrict__ xg,   // (B,81)
    const float* __restrict__ wsf,  // prep output
    const float* __restrict__ fcb,  // (4,)
    float* __restrict__ out)        // (B,4)
{
    // epilogue-only scratch: 32 rows x 34 dw per wave
    __shared__ u32 lds_scr[4 * 1088];
    __shared__ __align__(16) float lws[SMALL_FLOATS];

    const int tid  = threadIdx.x;
    const int lane = tid & 63;
    const int wid  = tid >> 6;
    const int h    = lane >> 5;          // half: conv1 channels 8h..8h+7
    const bool h0  = (h == 0);
    const int s    = lane & 31;          // sample-in-wave
    u32* scr = lds_scr + wid * 1088;

    if (tid < SMALL_FLOATS / 4)
        ((f4*)lws)[tid] = ((const f4*)(wsf + OFF_SMALL))[tid];
    __syncthreads();

    const v2f* w1p  = (const v2f*)(lws + S_W1P);
    const v2f* b1p  = (const v2f*)(lws + S_B1P);
    const v2f* fcwp = (const v2f*)(lws + S_FCWP);

    const int samp = blockIdx.x * 128 + wid * 32 + s;   // this lane's sample
    const float* xs = xg + (long long)samp * 81;

    const u32x4* bfrag_g = (const u32x4*)wsf;   // [pi*3+kb][lane] x 16B

    f32x16 acc{};                        // rows = samples 0..31 of this wave

    float xb[4][8], xbn[4][8];
    LOADB(xbn, 0);                       // prime the pipeline

    #pragma unroll 1                     // rolled: body fits I$
    for (int pi = 0; pi < 3; ++pi) {
        // ---- consume prefetched band (vmcnt wait lands here) ----
        #pragma unroll
        for (int r = 0; r < 4; ++r)
            #pragma unroll
            for (int c = 0; c < 8; ++c) {
                float v = xbn[r][c];
                asm volatile("" : "+v"(v));      // pin: no sink/remat
                xb[r][c] = v;
            }
        // ---- issue next band's x loads + this band's B-frag loads now ----
        if (pi < 2) LOADB(xbn, pi + 1);
        u32x4 bfr[3];
        #pragma unroll
        for (int kb = 0; kb < 3; ++kb)
            bfr[kb] = bfrag_g[(pi * 3 + kb) * 64 + lane];
        __builtin_amdgcn_sched_barrier(0);

        // ---- conv1 (channels 8h..8h+7) + pool + sigmoid -> pk[12] ----
        u32 pk[12];
        #pragma unroll
        for (int opl = 0; opl < 4; ++opl) {      // local channel pair
            const int gop = 4 * h + opl;         // global pair index
            v2f wv[9];
            #pragma unroll
            for (int k = 0; k < 9; ++k) wv[k] = w1p[gop * 9 + k];
            const v2f bb = b1p[gop];
            v2f vm[3];
            #pragma unroll
            for (int pj = 0; pj < 3; ++pj) {
                v2f vmax;
                #pragma unroll
                for (int dh = 0; dh < 2; ++dh)
                    #pragma unroll
                    for (int dw = 0; dw < 2; ++dw) {
                        v2f sacc = bb;
                        #pragma unroll
                        for (int i = 0; i < 3; ++i)
                            #pragma unroll
                            for (int jj = 0; jj < 3; ++jj) {
                                float xv = xb[dh + i][2 * pj + dw + jj];
                                sacc = __builtin_elementwise_fma(
                                           (v2f){xv, xv}, wv[i * 3 + jj], sacc);
                            }
                        if (dh == 0 && dw == 0) vmax = sacc;
                        else vmax = __builtin_elementwise_max(vmax, sacc);
                    }
                vm[pj] = vmax;
            }
            float s00 = sig2(vm[0].x), s01 = sig2(vm[1].x), s02 = sig2(vm[2].x);
            float s10 = sig2(vm[0].y), s11 = sig2(vm[1].y), s12 = sig2(vm[2].y);
            pk[3 * opl + 0] = pack_bf(s00, s01);
            pk[3 * opl + 1] = pack_bf(s02, s10);
            pk[3 * opl + 2] = pack_bf(s11, s12);
        }

        // ---- half-swap of pk[4..7]; A-frags; 3 MFMA ----
        u32 recv[4];
        #pragma unroll
        for (int i = 0; i < 4; ++i)
            recv[i] = (u32)__shfl_xor((int)pk[4 + i], 32);

        #pragma unroll
        for (int kb = 0; kb < 3; ++kb) {
            u32 ad[4];
            #pragma unroll
            for (int i = 0; i < 4; ++i) {
                ad[i] = (kb == 0) ? (h0 ? pk[i]     : recv[i])
                      : (kb == 1) ? (h0 ? pk[8 + i] : pk[i])
                                  : (h0 ? recv[i]   : pk[8 + i]);
            }
            u32x4 aw; aw.x = ad[0]; aw.y = ad[1]; aw.z = ad[2]; aw.w = ad[3];
            acc = __builtin_amdgcn_mfma_f32_32x32x16_bf16(
                      __builtin_bit_cast(bf16x8, aw),
                      __builtin_bit_cast(bf16x8, bfr[kb]), acc, 0, 0, 0);
        }
    }

    // ---- bias + sigmoid on C-layout regs, transpose via LDS ----
    // C/D: col(oc) = lane&31, row(sample) = (reg&3)+8*(reg>>2)+4*(lane>>5)
    const float b2v = lws[S_B2S + s];
    #pragma unroll
    for (int r = 0; r < 16; ++r) {
        const int srow = (r & 3) + 8 * (r >> 2) + 4 * h;
        scr[srow * 34 + s] = __builtin_bit_cast(u32, sig2(acc[r] + b2v));
    }

    // ---- fc: lane handles sample s, outputs 2h and 2h+1 ----
    v2f h2[16];
    #pragma unroll
    for (int j = 0; j < 16; ++j)
        h2[j] = *(const v2f*)((const float*)scr + s * 34 + 2 * j);

    const v2f* fA = fcwp + (2 * h) * 16;
    const v2f* fB = fcwp + (2 * h + 1) * 16;
    v2f aA = h2[0] * fA[0], aB = h2[0] * fB[0];
    #pragma unroll
    for (int j = 1; j < 16; ++j) {
        aA = __builtin_elementwise_fma(h2[j], fA[j], aA);
        aB = __builtin_elementwise_fma(h2[j], fB[j], aB);
    }
    float2 res = make_float2(fcb[2 * h] + aA.x + aA.y,
                             fcb[2 * h + 1] + aB.x + aB.y);
    ((float2*)out)[samp * 2 + h] = res;
}

extern "C" void kernel_launch(void* const* d_in, const int* in_sizes, int n_in,
                              void* d_out, int out_size, void* d_ws, size_t ws_size,
                              hipStream_t stream) {
    const float* x   = (const float*)d_in[0];
    const float* w1  = (const float*)d_in[1];
    const float* b1  = (const float*)d_in[2];
    const float* w2  = (const float*)d_in[3];
    const float* b2  = (const float*)d_in[4];
    const float* fcw = (const float*)d_in[5];
    const float* fcb = (const float*)d_in[6];
    float* out = (float*)d_out;
    float* ws  = (float*)d_ws;        // ~10.5 KB used

    prep_kernel<<<dim3((PREP_ITEMS + 255) / 256), dim3(256), 0, stream>>>(
        w1, b1, w2, b2, fcw, ws);

    const int nB = in_sizes[0] / 81;  // 131072; 128 samples per block
    olcnn_kernel<<<dim3(nB / 128), dim3(BLOCK), 0, stream>>>(x, ws, fcb, out);
}